// Round 1
// 1404.621 us; speedup vs baseline: 1.0804x; 1.0804x over previous
//
#include <hip/hip_runtime.h>
#include <stdint.h>
#include <stddef.h>

#define N_ 2048
#define D_ 64
#define INNER_ 32
#define HIDDEN_ 2048
#define CLASSES_ 10
#define P_ 2016
#define K_ (P_ * INNER_)      // 64512
#define SPLITK 4
#define KCHUNK (K_ / SPLITK)  // 16128
// fallback-kernel tile
#define BM 128
#define BN 128
#define BK 32
// main gemm tile
#define TBM 256
#define TBN 256
#define TBK 16                // per-K-tile depth; 4 ring buffers fit in 64 KB LDS
#define NBUF 4

typedef __bf16 bf16x8 __attribute__((ext_vector_type(8)));
typedef __bf16 bf16x4 __attribute__((ext_vector_type(4)));
typedef float f32x16 __attribute__((ext_vector_type(16)));
typedef float f32x4v __attribute__((ext_vector_type(4)));
typedef float f32x2v __attribute__((ext_vector_type(2)));
typedef __attribute__((address_space(1))) void gvoid_t;
typedef __attribute__((address_space(3))) void lvoid_t;

// ---------------- stage 1: u[n, p*32+i] = relu(x[n,ii]*Wu[p,0,i] + x[n,jj]*Wu[p,1,i] + bu[p,i]) ----
// Block covers 4 n-rows x 1024 k (32 p): pair decode done once by 32 threads into LDS,
// Wu/bu loads amortized over 4 rows.
__global__ __launch_bounds__(256) void k_u(const float* __restrict__ x,
                                           const float* __restrict__ Wu,
                                           const float* __restrict__ bu,
                                           __bf16* __restrict__ u) {
  const int t = threadIdx.x;
  const int n0 = blockIdx.y * 4;
  __shared__ float xs[4][D_];
  __shared__ int iis[32], jjs[32];
  xs[t >> 6][t & 63] = x[(size_t)(n0 + (t >> 6)) * D_ + (t & 63)];
  if (t < 32) {
    const int p = blockIdx.x * 32 + t;
    int ii = (int)floorf((127.0f - sqrtf(16129.0f - 8.0f * (float)p)) * 0.5f);
    int off = ii * 63 - (ii * (ii - 1)) / 2;
    while (p >= off + (63 - ii)) { off += 63 - ii; ++ii; }
    while (p < off)              { --ii; off -= 63 - ii; }
    iis[t] = ii;
    jjs[t] = (p - off) + ii + 1;
  }
  __syncthreads();
  const int k0 = blockIdx.x * 1024 + t * 4;
  const int pl = t >> 3;          // local p index 0..31
  const int i0 = (t & 7) * 4;
  const int p  = blockIdx.x * 32 + pl;
  const float4 w0 = *(const float4*)(Wu + (size_t)p * 64 + i0);
  const float4 w1 = *(const float4*)(Wu + (size_t)p * 64 + 32 + i0);
  const float4 bb = *(const float4*)(bu + (size_t)p * 32 + i0);
  const int ii = iis[pl], jj = jjs[pl];
#pragma unroll
  for (int nn = 0; nn < 4; ++nn) {
    const float xi = xs[nn][ii], xj = xs[nn][jj];
    bf16x4 r;
    r[0] = (__bf16)fmaxf(fmaf(xi, w0.x, fmaf(xj, w1.x, bb.x)), 0.0f);
    r[1] = (__bf16)fmaxf(fmaf(xi, w0.y, fmaf(xj, w1.y, bb.y)), 0.0f);
    r[2] = (__bf16)fmaxf(fmaf(xi, w0.z, fmaf(xj, w1.z, bb.z)), 0.0f);
    r[3] = (__bf16)fmaxf(fmaf(xi, w0.w, fmaf(xj, w1.w, bb.w)), 0.0f);
    *(bf16x4*)(u + (size_t)(n0 + nn) * K_ + k0) = r;
  }
}

// ---------------- stage 1b: WvT[h][k] = bf16(Wv[k][h]) — 64x64 LDS transpose, 16B / 128B-coalesced stores ----
__global__ __launch_bounds__(256) void k_tr(const float* __restrict__ Wv,
                                            __bf16* __restrict__ BT) {
  __shared__ float ls[64][65];
  const int t = threadIdx.x;
  const int k0 = blockIdx.x * 64, h0 = blockIdx.y * 64;
  const int c4 = (t & 15) * 4, r0 = t >> 4;
#pragma unroll
  for (int s = 0; s < 4; ++s) {
    const int r = r0 + 16 * s;
    const float4 vv = *(const float4*)(Wv + (size_t)(k0 + r) * HIDDEN_ + h0 + c4);
    ls[r][c4] = vv.x; ls[r][c4 + 1] = vv.y; ls[r][c4 + 2] = vv.z; ls[r][c4 + 3] = vv.w;
  }
  __syncthreads();
#pragma unroll
  for (int s = 0; s < 2; ++s) {
    const int item = s * 256 + t;
    const int h = item >> 3;      // 0..63
    const int kch = item & 7;     // 8-elem k chunk
    bf16x8 o;
#pragma unroll
    for (int j = 0; j < 8; ++j) o[j] = (__bf16)ls[kch * 8 + j][h];
    *(bf16x8*)(BT + (size_t)(h0 + h) * K_ + k0 + kch * 8) = o;
  }
}

// ---------------- stage 2 (main): 256x256 tile, 32x32x16 MFMA ----
// Ring-4 LDS buffers (TBK=16, 16 KB each = 64 KB total), counted-vmcnt pipeline (T3+T4):
//   per K-tile t: {6x ds_read_b128 frags(buf t%4); 2x global_load_lds staging T_{t+3};
//                  s_barrier; setprio(1) 8x MFMA setprio(0); s_waitcnt vmcnt(4); s_barrier}
// Gate soundness: each wave certifies ITS OWN T_{t+1} staging batch (2 gll) via vmcnt(4)
// (the 4 newer = batches T_{t+2},T_{t+3}); the trailing s_barrier broadcasts the certificate
// to all waves before anyone reads buf (t+1)%4. vmcnt never drains to 0 in the main loop:
// 3 K-tiles of loads stay in flight across barriers. Tail peels gates 4 -> 2 -> 0.
// Swizzle: row stride 32 B; LDS (row,cpos) holds global 16B-chunk cpos^((row>>2)&1);
// frag read cpos = khalf ^ ((row>>2)&1) -> 8 consecutive rows cover all 8 bank-slots.
__global__ __launch_bounds__(512, 2) void k_gemm3(const __bf16* __restrict__ A,   // u [N_][K_]
                                                  const __bf16* __restrict__ BT,  // WvT [HIDDEN_][K_]
                                                  float* __restrict__ part) {
  __shared__ __align__(16) __bf16 lds[NBUF][2][TBM][TBK];  // [buf][op][row][k] = 64 KB

  const int t = threadIdx.x;
  const int lane = t & 63;
  const int w = t >> 6;                 // 0..7
  const int wm = w & 3, wn = w >> 2;    // 4x2 wave grid, wave tile 64x128
  const int l31 = lane & 31, khalf = lane >> 5;

  // XCD-aware swizzle: XCD g hosts bm in [(g>>2)*4,+4), bn in [(g&3)*2,+2), all kc
  const int id = blockIdx.x;
  const int g = id & 7, s = id >> 3;
  const int bm = ((g >> 2) << 2) + (s & 3);
  const int bn = ((g & 3) << 1) + ((s >> 2) & 1);
  const int kc = s >> 3;
  const int mbase = bm * TBM, hbase = bn * TBN;

  // staging: per K-tile each plane is 8 KB = 512 threads x 16 B.
  // thread t covers LDS byte t*16 -> row = t>>1, chunk-pos = t&1; source chunk pre-swizzled.
  const int srow = t >> 1;
  const int sgc = (t & 1) ^ ((srow >> 2) & 1);
  const __bf16* gA = A + (size_t)(mbase + srow) * K_ + (size_t)kc * KCHUNK + sgc * 8;
  const __bf16* gB = BT + (size_t)(hbase + srow) * K_ + (size_t)kc * KCHUNK + sgc * 8;
  const uint32_t lOff = (uint32_t)((t & ~63) * 16);  // wave-uniform base; HW adds lane*16
  char* ldsbase = (char*)&lds[0][0][0][0];

  // fragment LDS element offsets within one buffer (A plane at 0, B plane at +4096 elems)
  int aoff[2], boff[4];
#pragma unroll
  for (int mf = 0; mf < 2; ++mf) {
    const int row = wm * 64 + mf * 32 + l31;
    const int cpos = khalf ^ ((row >> 2) & 1);
    aoff[mf] = row * TBK + cpos * 8;
  }
#pragma unroll
  for (int nf = 0; nf < 4; ++nf) {
    const int row = wn * 128 + nf * 32 + l31;
    const int cpos = khalf ^ ((row >> 2) & 1);
    boff[nf] = TBM * TBK + row * TBK + cpos * 8;
  }

  f32x16 acc[2][4] = {};

#define STAGE_TILE(BUF)                                                                        \
  do {                                                                                         \
    char* dst_ = ldsbase + (size_t)(BUF) * 16384;                                              \
    __builtin_amdgcn_global_load_lds((gvoid_t*)(uintptr_t)gA,                                  \
                                     (lvoid_t*)(uint32_t)(uintptr_t)(dst_ + lOff), 16, 0, 0);  \
    __builtin_amdgcn_global_load_lds((gvoid_t*)(uintptr_t)gB,                                  \
                                     (lvoid_t*)(uint32_t)(uintptr_t)(dst_ + 8192 + lOff), 16, 0, 0); \
    gA += TBK;                                                                                 \
    gB += TBK;                                                                                 \
  } while (0)

#define FRAG_READS(T)                                                                          \
  const __bf16* plane = (const __bf16*)(ldsbase + (size_t)((T) & 3) * 16384);                  \
  bf16x8 av[2], bv4[4];                                                                        \
  _Pragma("unroll") for (int mf = 0; mf < 2; ++mf)                                             \
      av[mf] = *(const bf16x8*)(plane + aoff[mf]);                                             \
  _Pragma("unroll") for (int nf = 0; nf < 4; ++nf)                                             \
      bv4[nf] = *(const bf16x8*)(plane + boff[nf]);

#define MFMA_CLUSTER()                                                                         \
  __builtin_amdgcn_s_setprio(1);                                                               \
  _Pragma("unroll") for (int mf = 0; mf < 2; ++mf)                                             \
      _Pragma("unroll") for (int nf = 0; nf < 4; ++nf)                                         \
          acc[mf][nf] = __builtin_amdgcn_mfma_f32_32x32x16_bf16(av[mf], bv4[nf],               \
                                                                acc[mf][nf], 0, 0, 0);         \
  __builtin_amdgcn_s_setprio(0);

  // prologue: stage T0..T2 into bufs 0..2; certify T0 (4 newer = T1,T2 batches)
  STAGE_TILE(0);
  STAGE_TILE(1);
  STAGE_TILE(2);
  asm volatile("s_waitcnt vmcnt(4)" ::: "memory");
  __builtin_amdgcn_s_barrier();
  __builtin_amdgcn_sched_barrier(0);

  const int ksteps = KCHUNK / TBK;  // 1008

  for (int t0 = 0; t0 < ksteps - 3; ++t0) {
    FRAG_READS(t0);
    STAGE_TILE((t0 + 3) & 3);
    __builtin_amdgcn_s_barrier();
    MFMA_CLUSTER();
    asm volatile("s_waitcnt vmcnt(4)" ::: "memory");  // certify T_{t0+1}
    __builtin_amdgcn_s_barrier();
    __builtin_amdgcn_sched_barrier(0);
  }
  {  // t = ksteps-3: no staging left; certify T_{ksteps-2} (2 newer = T_{ksteps-1} batch)
    FRAG_READS(ksteps - 3);
    __builtin_amdgcn_s_barrier();
    MFMA_CLUSTER();
    asm volatile("s_waitcnt vmcnt(2)" ::: "memory");
    __builtin_amdgcn_s_barrier();
    __builtin_amdgcn_sched_barrier(0);
  }
  {  // t = ksteps-2: certify T_{ksteps-1}
    FRAG_READS(ksteps - 2);
    __builtin_amdgcn_s_barrier();
    MFMA_CLUSTER();
    asm volatile("s_waitcnt vmcnt(0)" ::: "memory");
    __builtin_amdgcn_s_barrier();
    __builtin_amdgcn_sched_barrier(0);
  }
  {  // t = ksteps-1: last tile
    FRAG_READS(ksteps - 1);
    __builtin_amdgcn_s_barrier();
    MFMA_CLUSTER();
  }
#undef STAGE_TILE
#undef FRAG_READS
#undef MFMA_CLUSTER

  // epilogue: 32x32 C/D layout col=lane&31, row=(reg&3)+8*(reg>>2)+4*(lane>>5)
  float* op = part + ((size_t)kc * N_ + mbase + wm * 64) * HIDDEN_ + hbase + wn * 128;
#pragma unroll
  for (int mf = 0; mf < 2; ++mf)
#pragma unroll
    for (int nf = 0; nf < 4; ++nf)
#pragma unroll
      for (int rg = 0; rg < 16; ++rg) {
        const int row = mf * 32 + (rg & 3) + 8 * (rg >> 2) + 4 * khalf;
        op[(size_t)row * HIDDEN_ + nf * 32 + l31] = acc[mf][nf][rg];
      }
}

// ---------------- stage 2 (fallback, ws too small): in-kernel B convert ----
__global__ __launch_bounds__(256) void k_gemm_fb(const __bf16* __restrict__ A,
                                                 const float* __restrict__ Bv,
                                                 float* __restrict__ part) {
  __shared__ __bf16 As[BM][BK];
  __shared__ __bf16 BsT[BN][36];

  const int t = threadIdx.x;
  const int lane = t & 63;
  const int w = t >> 6, wm = w >> 1, wn = w & 1;
  const int l15 = lane & 15, q = lane >> 4;
  const int bn = blockIdx.x, bm = blockIdx.y, kc = blockIdx.z;
  const int mbase = bm * BM, hbase = bn * BN;
  const int n0 = (t & 63) * 2;
  const int kq = t >> 6;
  const int kx = (q ^ ((l15 >> 1) & 3)) * 8;

  const bf16x8* ap[4];
  const bf16x8* bp[4];
#pragma unroll
  for (int mf = 0; mf < 4; ++mf) ap[mf] = (const bf16x8*)&As[wm * 64 + mf * 16 + l15][kx];
#pragma unroll
  for (int nf = 0; nf < 4; ++nf) bp[nf] = (const bf16x8*)&BsT[wn * 64 + nf * 16 + l15][q * 8];

  f32x4v acc[4][4] = {};

  const int ksteps = KCHUNK / BK;
  for (int ks = 0; ks < ksteps; ++ks) {
    const int kbase = kc * KCHUNK + ks * BK;
    const float* gb = Bv + (size_t)(kbase + kq * 8) * HIDDEN_ + hbase + n0;
    f32x2v f[8];
#pragma unroll
    for (int qq = 0; qq < 8; ++qq) f[qq] = *(const f32x2v*)(gb + (size_t)qq * HIDDEN_);

    __syncthreads();
#pragma unroll
    for (int r = 0; r < 2; ++r) {
      const int flat = r * 256 + t;
      const int row = flat >> 2;
      const int gc = (flat & 3) ^ ((row >> 1) & 3);
      const __bf16* ga = A + (size_t)(mbase + row) * K_ + kbase + gc * 8;
      void* lp = (char*)&As[0][0] + (size_t)(r * 256 + (t & ~63)) * 16;
      __builtin_amdgcn_global_load_lds((gvoid_t*)(uintptr_t)ga,
                                       (lvoid_t*)(uint32_t)(uintptr_t)lp, 16, 0, 0);
    }
    bf16x8 c0, c1;
#pragma unroll
    for (int qq = 0; qq < 8; ++qq) { c0[qq] = (__bf16)f[qq][0]; c1[qq] = (__bf16)f[qq][1]; }
    *(bf16x8*)&BsT[n0][kq * 8]     = c0;
    *(bf16x8*)&BsT[n0 + 1][kq * 8] = c1;

    __syncthreads();

    bf16x8 av[4], bv4[4];
#pragma unroll
    for (int mf = 0; mf < 4; ++mf) av[mf] = *ap[mf];
#pragma unroll
    for (int nf = 0; nf < 4; ++nf) bv4[nf] = *bp[nf];
#pragma unroll
    for (int mf = 0; mf < 4; ++mf)
#pragma unroll
      for (int nf = 0; nf < 4; ++nf)
        acc[mf][nf] = __builtin_amdgcn_mfma_f32_16x16x32_bf16(av[mf], bv4[nf], acc[mf][nf], 0, 0, 0);
  }

  float* op = part + ((size_t)kc * N_ + mbase + wm * 64) * HIDDEN_ + hbase + wn * 64;
#pragma unroll
  for (int mf = 0; mf < 4; ++mf)
#pragma unroll
    for (int nf = 0; nf < 4; ++nf)
#pragma unroll
      for (int r = 0; r < 4; ++r)
        op[(size_t)(mf * 16 + q * 4 + r) * HIDDEN_ + nf * 16 + l15] = acc[mf][nf][r];
}

// ---------------- stage 3: v = relu(sum(partials) + bv) ----------------
__global__ __launch_bounds__(256) void k_reduce(const float* __restrict__ part,
                                                const float* __restrict__ bv,
                                                float* __restrict__ v) {
  const size_t i = ((size_t)blockIdx.x * 256 + threadIdx.x) * 4;
  f32x4v s = *(const f32x4v*)(part + i);
  s += *(const f32x4v*)(part + (size_t)1 * N_ * HIDDEN_ + i);
  s += *(const f32x4v*)(part + (size_t)2 * N_ * HIDDEN_ + i);
  s += *(const f32x4v*)(part + (size_t)3 * N_ * HIDDEN_ + i);
  s += *(const f32x4v*)(bv + (i & (HIDDEN_ - 1)));
  s[0] = fmaxf(s[0], 0.0f);
  s[1] = fmaxf(s[1], 0.0f);
  s[2] = fmaxf(s[2], 0.0f);
  s[3] = fmaxf(s[3], 0.0f);
  *(f32x4v*)(v + i) = s;
}

// ---------------- stage 4: out = v @ Wo + bo (wave per row) ----------------
__global__ __launch_bounds__(256) void k_out(const float* __restrict__ v,
                                             const float* __restrict__ Wo,
                                             const float* __restrict__ bo,
                                             float* __restrict__ out) {
  const int lane = threadIdx.x & 63;
  const int n = blockIdx.x * 4 + (threadIdx.x >> 6);
  float acc[CLASSES_];
#pragma unroll
  for (int c = 0; c < CLASSES_; ++c) acc[c] = 0.0f;
  for (int h0 = lane * 4; h0 < HIDDEN_; h0 += 256) {
    const f32x4v vv = *(const f32x4v*)(v + (size_t)n * HIDDEN_ + h0);
#pragma unroll
    for (int qq = 0; qq < 4; ++qq) {
      const float s = vv[qq];
      const float* wo = Wo + (size_t)(h0 + qq) * CLASSES_;
#pragma unroll
      for (int c = 0; c < CLASSES_; ++c) acc[c] = fmaf(s, wo[c], acc[c]);
    }
  }
#pragma unroll
  for (int c = 0; c < CLASSES_; ++c) {
#pragma unroll
    for (int o = 32; o > 0; o >>= 1) acc[c] += __shfl_down(acc[c], o);
  }
  if (lane == 0) {
#pragma unroll
    for (int c = 0; c < CLASSES_; ++c) out[(size_t)n * CLASSES_ + c] = acc[c] + bo[c];
  }
}

extern "C" void kernel_launch(void* const* d_in, const int* in_sizes, int n_in,
                              void* d_out, int out_size, void* d_ws, size_t ws_size,
                              hipStream_t stream) {
  const float* x  = (const float*)d_in[0];
  const float* Wu = (const float*)d_in[1];
  const float* bu = (const float*)d_in[2];
  const float* Wv = (const float*)d_in[3];
  const float* bv = (const float*)d_in[4];
  const float* Wo = (const float*)d_in[5];
  const float* bo = (const float*)d_in[6];
  float* out = (float*)d_out;

  char* ws = (char*)d_ws;
  const size_t SZ_BT = (size_t)HIDDEN_ * K_ * 2;          // 264,241,152
  const size_t SZ_U  = (size_t)N_ * K_ * 2;               // 264,241,152
  const size_t SZ_P  = (size_t)SPLITK * N_ * HIDDEN_ * 4; // 67,108,864
  const size_t NEED  = SZ_BT + SZ_U + SZ_P;               // 595,591,168

  if (ws_size >= NEED) {
    __bf16* BT  = (__bf16*)ws;
    __bf16* u   = (__bf16*)(ws + SZ_BT);
    float* part = (float*)(ws + SZ_BT + SZ_U);
    float* v    = (float*)ws;  // aliases BT (dead after gemm)

    k_u<<<dim3(K_ / 1024, N_ / 4), 256, 0, stream>>>(x, Wu, bu, u);
    k_tr<<<dim3(K_ / 64, HIDDEN_ / 64), 256, 0, stream>>>(Wv, BT);
    k_gemm3<<<dim3((HIDDEN_ / TBN) * (N_ / TBM) * SPLITK), 512, 0, stream>>>(u, BT, part);
    k_reduce<<<dim3((N_ * HIDDEN_) / 1024), 256, 0, stream>>>(part, bv, v);
    k_out<<<dim3(N_ / 4), 256, 0, stream>>>(v, Wo, bo, out);
  } else {
    __bf16* u   = (__bf16*)ws;
    float* part = (float*)(ws + SZ_U);
    float* v    = (float*)(ws + SZ_U + SZ_P);

    k_u<<<dim3(K_ / 1024, N_ / 4), 256, 0, stream>>>(x, Wu, bu, u);
    k_gemm_fb<<<dim3(HIDDEN_ / BN, N_ / BM, SPLITK), 256, 0, stream>>>(u, Wv, part);
    k_reduce<<<dim3((N_ * HIDDEN_) / 1024), 256, 0, stream>>>(part, bv, v);
    k_out<<<dim3(N_ / 4), 256, 0, stream>>>(v, Wo, bo, out);
  }
}